// Round 10
// baseline (458.622 us; speedup 1.0000x reference)
//
#include <hip/hip_runtime.h>
#include <hip/hip_bf16.h>
#include <stdint.h>

#define DIMV 1910
#define KP   1920                 // padded K — multiple of 64
#define NT   60                   // K tiles of 32 per m-tile
#define TT   240                  // total tiles (4 m-tiles x NT)
#define PHI_F  1.6180339887498949f
#define BETA_F 0.3819660112501051f

typedef __attribute__((ext_vector_type(4))) float f32x4;
typedef __attribute__((ext_vector_type(8))) short bf16x8;
typedef __attribute__((ext_vector_type(8))) unsigned short u16x8;

__device__ __forceinline__ void gl16(const void* g, void* l) {
    __builtin_amdgcn_global_load_lds(
        (const __attribute__((address_space(1))) void*)(uintptr_t)g,
        (__attribute__((address_space(3))) void*)(uint32_t)(uintptr_t)l,
        16, 0, 0);
}

// Fused prep: even blocks convert x fp32 -> bf16 [M][1920]; odd blocks scatter
// COO atomics into Wd (overlapped: conv is BW-bound, scatter latency-bound).
__global__ void k_prep(const float* __restrict__ x, unsigned short* __restrict__ xb, int total8,
                       const int* __restrict__ ridx, const int* __restrict__ cidx,
                       const float* __restrict__ vals, float* __restrict__ Wd, int nz) {
    const int tid  = threadIdx.x;
    const int half = (int)gridDim.x >> 1;
    const int b    = (int)blockIdx.x >> 1;
    const int stride = half * 256;
    if ((blockIdx.x & 1) == 0) {
        for (int i = b * 256 + tid; i < total8; i += stride) {
            int v = i * 8;
            int row = v / KP;
            int col = v - row * KP;
            u16x8 o;
            if (col + 8 <= DIMV) {
                const float2* s = (const float2*)(x + (size_t)row * DIMV + col);
                float2 f0 = s[0], f1 = s[1], f2 = s[2], f3 = s[3];
                float f[8] = {f0.x, f0.y, f1.x, f1.y, f2.x, f2.y, f3.x, f3.y};
#pragma unroll
                for (int j = 0; j < 8; ++j) {
                    __hip_bfloat16 bb = __float2bfloat16(f[j]);
                    o[j] = *reinterpret_cast<unsigned short*>(&bb);
                }
            } else {
#pragma unroll
                for (int j = 0; j < 8; ++j) {
                    int c = col + j;
                    float fv = (c < DIMV) ? x[(size_t)row * DIMV + c] : 0.f;
                    __hip_bfloat16 bb = __float2bfloat16(fv);
                    o[j] = *reinterpret_cast<unsigned short*>(&bb);
                }
            }
            *(u16x8*)(xb + (size_t)v) = o;
        }
    } else {
        for (int i = b * 256 + tid; i < nz; i += stride)
            atomicAdd(Wd + (size_t)ridx[i] * DIMV + cidx[i], vals[i]);
    }
}

// W' = W + PHI*I, [1920 rows][1920 cols] bf16
__global__ void k_build_w(const float* __restrict__ Wd, unsigned short* __restrict__ Wb, int total8) {
    int stride = gridDim.x * blockDim.x;
    for (int i = blockIdx.x * blockDim.x + threadIdx.x; i < total8; i += stride) {
        int v = i * 8;
        int n = v / KP;
        int k = v - n * KP;
        u16x8 o;
#pragma unroll
        for (int j = 0; j < 8; ++j) {
            int kk = k + j;
            float fv = (n < DIMV && kk < DIMV) ? Wd[(size_t)n * DIMV + kk] : 0.f;
            if (kk == n && n < DIMV) fv += PHI_F;
            __hip_bfloat16 b = __float2bfloat16(fv);
            o[j] = *reinterpret_cast<unsigned short*>(&b);
        }
        *(u16x8*)(Wb + (size_t)v) = o;
    }
}

// C[m][n] = BETA * sum_k A[m][k] * B[n][k];  A = xb bf16 [32768][1920]
// Tile 256x128, BK=32, 256 threads (4 waves: 2M x 2N), per-wave 128x64.
// TWO INDEPENDENT BLOCKS PER CU (64KB LDS each): waves from different blocks
// share each SIMD but have separate barrier domains, so one block's MFMA
// clusters fill the matrix pipe while the other block sits in its read /
// barrier window — the overlap that a single 512-thread lockstep block
// cannot express (r6/r7/r9 all plateaued at MfmaUtil ~40%).
// PERSISTENT: grid 512 = 16 bn x 32 bmg, 4 m-tiles each (bm = mt*32+bmg).
// LDS: A 3-deep x 16KB @ 0/16384/32768, B 2-deep x 8KB @ 49152/57344.
// Per tile, 2 phases x 16 MFMA: P0 {read aLo+b(8), stage B(t+1)x2, bar,
// lgkm0, MFMA16, bar}; P1 {read aHi(4), stage A(t+2)x4, bar, lgkm0, MFMA16,
// vmcnt(4) gate, bar}. Race-invariant (r8 lesson): every ds_read follows a
// gate that ALL waves executed before a barrier; A 3-deep means the in-phase
// stage never targets the slot being read. Gate math (FIFO): at P1-end queue
// = A(t+1)[<=4] B(t+1)[2] A(t+2)[4]; vmcnt(4) retires A(t+1),B(t+1), keeps
// A(t+2) in flight. Swizzle: rows 64B = 4 slots, phys = logical^((row>>1)&3),
// inverse pre-applied on global source (rule 21; r3 measured 0 conflicts).
__global__ __launch_bounds__(256, 2) void k_gemm(const short* __restrict__ A,
                                                 const short* __restrict__ B,
                                                 float* __restrict__ C) {
    __shared__ char lds[65536];

    const int bid = blockIdx.x;
    const int bn  = bid & 15;            // N column (0..15); bn%8 fixed per XCD
    const int bmg = bid >> 4;            // 0..31

    const int tid = threadIdx.x;
    const int w   = tid >> 6;
    const int l   = tid & 63;
    const int wm  = w >> 1;              // 0..1 (M)
    const int wn  = w & 1;               // 0..1 (N)
    const int fr  = l & 15;
    const int q   = l >> 4;              // 0..3

    // ---- staging geometry (pre-swizzled source, linear LDS dest) ----
    const int    srow = tid >> 2;                       // 0..63 row within a sweep
    const int    slt  = tid & 3;                        // phys 16B slot
    const size_t KPB  = (size_t)KP * 2;                 // 3840 bytes/row
    const int    swz  = (slt ^ ((srow >> 1) & 3)) * 16; // logical slot offset in source
    const char*  bSrc = (const char*)B + (size_t)(bn * 128 + srow) * KPB + swz;
    const size_t sweep = (size_t)64 * KPB;              // 64 rows
    char* stDst = lds + tid * 16;                       // one 4KB sweep per stage call

    // ---- fragment read offsets (swizzled slots; co uniform across mi/ni) ----
    const int co   = (q ^ ((fr >> 1) & 3)) * 16;
    const int aOff = (wm * 128 + fr) * 64 + co;         // + mi*1024, mi=0..7
    const int bOff = 49152 + (wn * 64 + fr) * 64 + co;  // + ni*1024, ni=0..3

    f32x4 acc[8][4] = {};
    bf16x8 aLo[4], aHi[4], b[4];

#define STAGE_A(src, kk_, slot, s) gl16((src) + (size_t)(s) * sweep + (size_t)(kk_) * 64, stDst + (slot) + (s) * 4096)
#define STAGE_B(kk_, slot, s)      gl16(bSrc  + (size_t)(s) * sweep + (size_t)(kk_) * 64, stDst + 49152 + (slot) + (s) * 4096)

    const char* aSrc0 = (const char*)A + (size_t)(bmg * 256 + srow) * KPB + swz;
    const size_t mstep = (size_t)8192 * KPB;

    // ---- prologue: A(0)->slot0, B(0)->bslot0, A(1)->slot1; keep A(1) in flight ----
#pragma unroll
    for (int s = 0; s < 4; ++s) STAGE_A(aSrc0, 0, 0, s);
#pragma unroll
    for (int s = 0; s < 2; ++s) STAGE_B(0, 0, s);
#pragma unroll
    for (int s = 0; s < 4; ++s) STAGE_A(aSrc0, 1, 16384, s);
    asm volatile("s_waitcnt vmcnt(4)" ::: "memory");
    __builtin_amdgcn_s_barrier();
    asm volatile("" ::: "memory");

    int boA = 0, stA = 32768;            // A read slot (t%3), stage slot ((t+2)%3)
    int boB = 0;                         // B read slot (t%2)*8192
    int kb = 1, k2 = 2;                  // (t+1)%NT (B stage), (t+2)%NT (A stage)
    int tkR = 0, mtR = 0;                // k-index / m-tile of tile t
    const char* aStage = aSrc0;          // A stage base (m-tile of t+2)

    for (int t = 0; t < TT; ++t) {
        const char* pa = lds + boA + aOff;
        const char* pb = lds + boB + bOff;
        const bool stb = (t + 1 < TT);
        const bool sta = (t + 2 < TT);

        // ======== P0: read aLo+b (8), stage B(t+1); MFMA mi0-3 ========
#pragma unroll
        for (int mi = 0; mi < 4; ++mi) aLo[mi] = *(const bf16x8*)(pa + mi * 1024);
#pragma unroll
        for (int ni = 0; ni < 4; ++ni) b[ni]   = *(const bf16x8*)(pb + ni * 1024);
        if (stb) { STAGE_B(kb, boB ^ 8192, 0); STAGE_B(kb, boB ^ 8192, 1); }
        asm volatile("" ::: "memory");
        __builtin_amdgcn_s_barrier();
        asm volatile("s_waitcnt lgkmcnt(0)" ::: "memory");
        __builtin_amdgcn_sched_barrier(0);
        __builtin_amdgcn_s_setprio(1);
#pragma unroll
        for (int mi = 0; mi < 4; ++mi)
#pragma unroll
            for (int ni = 0; ni < 4; ++ni)
                acc[mi][ni] = __builtin_amdgcn_mfma_f32_16x16x32_bf16(aLo[mi], b[ni], acc[mi][ni], 0, 0, 0);
        __builtin_amdgcn_s_setprio(0);
        asm volatile("" ::: "memory");
        __builtin_amdgcn_s_barrier();
        asm volatile("" ::: "memory");

        // ======== P1: read aHi (4), stage A(t+2); MFMA mi4-7; counted gate ========
#pragma unroll
        for (int mi = 0; mi < 4; ++mi) aHi[mi] = *(const bf16x8*)(pa + 4096 + mi * 1024);
        if (sta) { STAGE_A(aStage, k2, stA, 0); STAGE_A(aStage, k2, stA, 1);
                   STAGE_A(aStage, k2, stA, 2); STAGE_A(aStage, k2, stA, 3); }
        asm volatile("" ::: "memory");
        __builtin_amdgcn_s_barrier();
        asm volatile("s_waitcnt lgkmcnt(0)" ::: "memory");
        __builtin_amdgcn_sched_barrier(0);
        __builtin_amdgcn_s_setprio(1);
#pragma unroll
        for (int mi = 0; mi < 4; ++mi)
#pragma unroll
            for (int ni = 0; ni < 4; ++ni)
                acc[mi + 4][ni] = __builtin_amdgcn_mfma_f32_16x16x32_bf16(aHi[mi], b[ni], acc[mi + 4][ni], 0, 0, 0);
        __builtin_amdgcn_s_setprio(0);
        // retire A(t+1)+B(t+1) (+older stores); keep A(t+2)'s 4 in flight
        if (sta) { asm volatile("s_waitcnt vmcnt(4)" ::: "memory"); }
        else     { asm volatile("s_waitcnt vmcnt(0)" ::: "memory"); }
        __builtin_amdgcn_s_barrier();
        asm volatile("" ::: "memory");

        // ---- m-tile epilogue: issue stores (drained by later gates), zero acc ----
        if (tkR == NT - 1) {
            const int bm    = mtR * 32 + bmg;
            const int grow0 = bm * 256 + wm * 128 + q * 4;
            const int gcol0 = bn * 128 + wn * 64 + fr;
#pragma unroll
            for (int ei = 0; ei < 8; ++ei) {
#pragma unroll
                for (int ni = 0; ni < 4; ++ni) {
                    int gcol = gcol0 + ni * 16;
                    if (gcol < DIMV) {
                        size_t base = (size_t)(grow0 + ei * 16) * DIMV + gcol;
#pragma unroll
                        for (int r = 0; r < 4; ++r)
                            C[base + (size_t)r * DIMV] = BETA_F * acc[ei][ni][r];
                    }
                }
            }
            if (t + 1 < TT) {
#pragma unroll
                for (int ei = 0; ei < 8; ++ei)
#pragma unroll
                    for (int ni = 0; ni < 4; ++ni)
                        acc[ei][ni] = (f32x4)(0.f);
            }
            tkR = 0; ++mtR;
        } else ++tkR;

        // rotate buffers / lookahead counters
        boA = (boA == 32768) ? 0 : boA + 16384;
        stA = (stA == 32768) ? 0 : stA + 16384;
        boB ^= 8192;
        if (++kb == NT) kb = 0;
        if (++k2 == NT) { k2 = 0; aStage += mstep; }
    }
#undef STAGE_A
#undef STAGE_B
}

extern "C" void kernel_launch(void* const* d_in, const int* in_sizes, int n_in,
                              void* d_out, int out_size, void* d_ws, size_t ws_size,
                              hipStream_t stream) {
    const float* x    = (const float*)d_in[0];
    const int*   widx = (const int*)d_in[1];
    const float* wval = (const float*)d_in[2];
    float* out = (float*)d_out;

    const int nz = in_sizes[2];
    const int M  = in_sizes[0] / DIMV;      // 32768

    const size_t xb_bytes = (size_t)M * KP * 2;          // 125,829,120
    const size_t wb_bytes = (size_t)2048 * KP * 2;       //   7,864,320
    const size_t wd_bytes = (size_t)DIMV * DIMV * 4;     //  14,592,400
    char* ws = (char*)d_ws;
    unsigned short* xb = (unsigned short*)ws;
    unsigned short* Wb = (unsigned short*)(ws + xb_bytes);
    float*          Wd = (float*)(ws + xb_bytes + wb_bytes);
    if (ws_size < xb_bytes + wb_bytes + wd_bytes) return;

    hipMemsetAsync(Wd, 0, wd_bytes, stream);
    k_prep<<<2048, 256, 0, stream>>>(x, xb, M * KP / 8, widx, widx + nz, wval, Wd, nz);
    k_build_w<<<1800, 256, 0, stream>>>(Wd, Wb, KP * KP / 8);
    k_gemm<<<512, 256, 0, stream>>>((const short*)xb, (const short*)Wb, out);
}

// Round 11
// 388.677 us; speedup vs baseline: 1.1800x; 1.1800x over previous
//
#include <hip/hip_runtime.h>
#include <hip/hip_bf16.h>
#include <stdint.h>

#define DIMV 1910
#define KP   1920                 // padded K — multiple of 64
#define NT   30                   // K tiles of 64 per m-tile
#define TT   120                  // total tiles (4 m-tiles x NT)
#define PHI_F  1.6180339887498949f
#define BETA_F 0.3819660112501051f

typedef __attribute__((ext_vector_type(4))) float f32x4;
typedef __attribute__((ext_vector_type(8))) short bf16x8;
typedef __attribute__((ext_vector_type(8))) unsigned short u16x8;

__device__ __forceinline__ void gl16(const void* g, void* l) {
    __builtin_amdgcn_global_load_lds(
        (const __attribute__((address_space(1))) void*)(uintptr_t)g,
        (__attribute__((address_space(3))) void*)(uint32_t)(uintptr_t)l,
        16, 0, 0);
}

// Fused prep: even blocks convert x fp32 -> bf16 [M][1920]; odd blocks scatter
// COO atomics into Wd (overlapped: conv is BW-bound, scatter latency-bound).
__global__ void k_prep(const float* __restrict__ x, unsigned short* __restrict__ xb, int total8,
                       const int* __restrict__ ridx, const int* __restrict__ cidx,
                       const float* __restrict__ vals, float* __restrict__ Wd, int nz) {
    const int tid  = threadIdx.x;
    const int half = (int)gridDim.x >> 1;
    const int b    = (int)blockIdx.x >> 1;
    const int stride = half * 256;
    if ((blockIdx.x & 1) == 0) {
        for (int i = b * 256 + tid; i < total8; i += stride) {
            int v = i * 8;
            int row = v / KP;
            int col = v - row * KP;
            u16x8 o;
            if (col + 8 <= DIMV) {
                const float2* s = (const float2*)(x + (size_t)row * DIMV + col);
                float2 f0 = s[0], f1 = s[1], f2 = s[2], f3 = s[3];
                float f[8] = {f0.x, f0.y, f1.x, f1.y, f2.x, f2.y, f3.x, f3.y};
#pragma unroll
                for (int j = 0; j < 8; ++j) {
                    __hip_bfloat16 bb = __float2bfloat16(f[j]);
                    o[j] = *reinterpret_cast<unsigned short*>(&bb);
                }
            } else {
#pragma unroll
                for (int j = 0; j < 8; ++j) {
                    int c = col + j;
                    float fv = (c < DIMV) ? x[(size_t)row * DIMV + c] : 0.f;
                    __hip_bfloat16 bb = __float2bfloat16(fv);
                    o[j] = *reinterpret_cast<unsigned short*>(&bb);
                }
            }
            *(u16x8*)(xb + (size_t)v) = o;
        }
    } else {
        for (int i = b * 256 + tid; i < nz; i += stride)
            atomicAdd(Wd + (size_t)ridx[i] * DIMV + cidx[i], vals[i]);
    }
}

// W' = W + PHI*I, [1920 rows][1920 cols] bf16
__global__ void k_build_w(const float* __restrict__ Wd, unsigned short* __restrict__ Wb, int total8) {
    int stride = gridDim.x * blockDim.x;
    for (int i = blockIdx.x * blockDim.x + threadIdx.x; i < total8; i += stride) {
        int v = i * 8;
        int n = v / KP;
        int k = v - n * KP;
        u16x8 o;
#pragma unroll
        for (int j = 0; j < 8; ++j) {
            int kk = k + j;
            float fv = (n < DIMV && kk < DIMV) ? Wd[(size_t)n * DIMV + kk] : 0.f;
            if (kk == n && n < DIMV) fv += PHI_F;
            __hip_bfloat16 b = __float2bfloat16(fv);
            o[j] = *reinterpret_cast<unsigned short*>(&b);
        }
        *(u16x8*)(Wb + (size_t)v) = o;
    }
}

// C[m][n] = BETA * sum_k A[m][k] * B[n][k];  A = xb bf16 [32768][1920]
// Tile 256x256, BK=64, 512 threads (8 waves: 2M x 4N), per-wave 128x64.
// PERSISTENT flat tile loop t=0..119. A 3-deep + B 2-deep LDS bufs (160KB).
// 3 phases/tile (12/4/8 ds_reads, 16/16/32 MFMA). KEY CHANGE vs r7: no
// sched_barrier(0) pins — the ds_reads are compiler-visible, so hipcc hoists
// MFMAs past the asm lgkmcnt(0) with per-operand fine-grained lgkmcnt(N)
// (m97 evidence), letting the matrix pipe start while the LDS pipe drains.
// (r6-r10's sched_barrier(0) forced a full LDS drain before the first MFMA of
// every phase -> measured time == MFMA-pipe + LDS-pipe exactly, 40% plateau.)
// Race invariants unchanged: every ds_read follows an all-waves gate+barrier;
// stage targets never alias in-phase read slots (A 3-deep, B 2-deep);
// per-tile counted vmcnt(4) keeps A(t+2) in flight, drains A(t+1)+B(t+1).
// XCD-disjoint A: bmg=bid&31, bn=bid>>5 (FETCH 185MB verified r7/r9).
// Swizzle (rule 21): row=128B=8 slots, phys = logical ^ (row&7), inverse
// pre-applied on the global source; verified 0 conflicts (r2-r10).
__global__ __launch_bounds__(512, 2) void k_gemm(const short* __restrict__ A,
                                                 const short* __restrict__ B,
                                                 float* __restrict__ C) {
    __shared__ char lds[163840];   // A: 3 x 32KB @ 0/32768/65536; B: 2 x 32KB @ 98304/131072

    const int bid = blockIdx.x;
    const int bmg = bid & 31;            // XCD-private A row group (bmg%8 == XCD)
    const int bn  = bid >> 5;            // 0..7 N column

    const int tid = threadIdx.x;
    const int w   = tid >> 6;
    const int l   = tid & 63;
    const int wm  = w >> 2;              // 0..1 (M)
    const int wn  = w & 3;               // 0..3 (N)
    const int fr  = l & 15;
    const int q   = l >> 4;              // 0..3

    // ---- staging source (pre-swizzled), linear LDS dest ----
    const int    srow = tid >> 3;                       // 0..63 row within a sweep
    const size_t KPB  = (size_t)KP * 2;                 // 3840 bytes/row
    const int    swz  = ((tid & 7) ^ (srow & 7)) * 16;
    const char*  bSrc = (const char*)B + (size_t)(bn * 256 + srow) * KPB + swz;
    const size_t sweep = (size_t)64 * KPB;
    char* stDst = lds + tid * 16;

    // ---- fragment read offsets (swizzled slots) ----
    const int co0  = ((q    ) ^ (fr & 7)) * 16;         // kk=0
    const int co1  = ((4 + q) ^ (fr & 7)) * 16;         // kk=1
    const int aOff = (wm * 128 + fr) * 128;             // + mi*2048, mi=0..7
    const int bOff = (wn * 64 + fr) * 128;              // + ni*2048, ni=0..3

    f32x4 acc[8][4] = {};

#define STAGE_A(src, kk_, dstoff, s) gl16((src) + (size_t)(s) * sweep + (size_t)(kk_) * 128, stDst + (dstoff) + (s) * 8192)
#define STAGE_B(kk_, dstoff, s)      gl16(bSrc  + (size_t)(s) * sweep + (size_t)(kk_) * 128, stDst + 98304 + (dstoff) + (s) * 8192)

    const char* aSrc0 = (const char*)A + (size_t)(bmg * 256 + srow) * KPB + swz;
    const size_t mstep = (size_t)8192 * KPB;

    // ---- prologue: A(0)->slot0, B(0)->bufB0, A(1)->slot1; keep A(1) in flight ----
#pragma unroll
    for (int s = 0; s < 4; ++s) STAGE_A(aSrc0, 0, 0, s);
#pragma unroll
    for (int s = 0; s < 4; ++s) STAGE_B(0, 0, s);
#pragma unroll
    for (int s = 0; s < 4; ++s) STAGE_A(aSrc0, 1, 32768, s);
    asm volatile("s_waitcnt vmcnt(4)" ::: "memory");
    __builtin_amdgcn_s_barrier();
    asm volatile("" ::: "memory");

    // rotating state
    int boA = 0, stA = 65536;            // A read / stage buffer offsets (mod 3)
    int boB = 0, stB = 32768;            // B read / stage buffer offsets (mod 2)
    int tkR = 0;                         // tau % 30 (read tile k-index)
    int kb1 = 1;                         // (tau+1) % 30 (B stage k-index)
    int ka2 = 2;                         // (tau+2) % 30 (A stage k-index)
    int mtR = 0;                         // read m-tile
    const char* aStage = aSrc0;          // A stage row base (m-tile of tau+2)

    for (int t = 0; t < TT; ++t) {
        const char* pa = lds + boA + aOff;
        const char* pb = lds + 98304 + boB + bOff;
        const bool stb = (t + 1 < TT);
        const bool sta = (t + 2 < TT);
        bf16x8 a[4][2], b0[2][2], b1[2][2];

        // ======== P0: 12 ds_reads (A-lo, B0), stage B(t+1) s0,s1; MFMA (mh0,nh0) ========
#pragma unroll
        for (int mi = 0; mi < 4; ++mi) {
            a[mi][0] = *(const bf16x8*)(pa + mi * 2048 + co0);
            a[mi][1] = *(const bf16x8*)(pa + mi * 2048 + co1);
        }
#pragma unroll
        for (int ni = 0; ni < 2; ++ni) {
            b0[ni][0] = *(const bf16x8*)(pb + ni * 2048 + co0);
            b0[ni][1] = *(const bf16x8*)(pb + ni * 2048 + co1);
        }
        if (stb) { STAGE_B(kb1, stB, 0); STAGE_B(kb1, stB, 1); }
        asm volatile("" ::: "memory");
        __builtin_amdgcn_s_barrier();
        asm volatile("s_waitcnt lgkmcnt(0)" ::: "memory");
        __builtin_amdgcn_s_setprio(1);
#pragma unroll
        for (int kk = 0; kk < 2; ++kk)
#pragma unroll
            for (int mi = 0; mi < 4; ++mi)
#pragma unroll
                for (int ni = 0; ni < 2; ++ni)
                    acc[mi][ni] = __builtin_amdgcn_mfma_f32_16x16x32_bf16(a[mi][kk], b0[ni][kk], acc[mi][ni], 0, 0, 0);
        __builtin_amdgcn_s_setprio(0);
        asm volatile("" ::: "memory");
        __builtin_amdgcn_s_barrier();
        asm volatile("" ::: "memory");

        // ======== P1: 4 ds_reads (B1), stage B s2,s3 + A(t+2) s0,s1; MFMA (mh0,nh1) ========
#pragma unroll
        for (int ni = 0; ni < 2; ++ni) {
            b1[ni][0] = *(const bf16x8*)(pb + 4096 + ni * 2048 + co0);
            b1[ni][1] = *(const bf16x8*)(pb + 4096 + ni * 2048 + co1);
        }
        if (stb) { STAGE_B(kb1, stB, 2); STAGE_B(kb1, stB, 3); }
        if (sta) { STAGE_A(aStage, ka2, stA, 0); STAGE_A(aStage, ka2, stA, 1); }
        asm volatile("" ::: "memory");
        __builtin_amdgcn_s_barrier();
        asm volatile("s_waitcnt lgkmcnt(0)" ::: "memory");
        __builtin_amdgcn_s_setprio(1);
#pragma unroll
        for (int kk = 0; kk < 2; ++kk)
#pragma unroll
            for (int mi = 0; mi < 4; ++mi)
#pragma unroll
                for (int ni = 0; ni < 2; ++ni)
                    acc[mi][ni + 2] = __builtin_amdgcn_mfma_f32_16x16x32_bf16(a[mi][kk], b1[ni][kk], acc[mi][ni + 2], 0, 0, 0);
        __builtin_amdgcn_s_setprio(0);
        asm volatile("" ::: "memory");
        __builtin_amdgcn_s_barrier();
        asm volatile("" ::: "memory");

        // ======== P2: 8 ds_reads (A-hi), stage A s2,s3; MFMA (mh1,nh1)+(mh1,nh0); gate ========
#pragma unroll
        for (int mi = 0; mi < 4; ++mi) {
            a[mi][0] = *(const bf16x8*)(pa + 8192 + mi * 2048 + co0);
            a[mi][1] = *(const bf16x8*)(pa + 8192 + mi * 2048 + co1);
        }
        if (sta) { STAGE_A(aStage, ka2, stA, 2); STAGE_A(aStage, ka2, stA, 3); }
        asm volatile("" ::: "memory");
        __builtin_amdgcn_s_barrier();
        asm volatile("s_waitcnt lgkmcnt(0)" ::: "memory");
        __builtin_amdgcn_s_setprio(1);
#pragma unroll
        for (int kk = 0; kk < 2; ++kk)
#pragma unroll
            for (int mi = 0; mi < 4; ++mi)
#pragma unroll
                for (int ni = 0; ni < 2; ++ni)
                    acc[mi + 4][ni + 2] = __builtin_amdgcn_mfma_f32_16x16x32_bf16(a[mi][kk], b1[ni][kk], acc[mi + 4][ni + 2], 0, 0, 0);
#pragma unroll
        for (int kk = 0; kk < 2; ++kk)
#pragma unroll
            for (int mi = 0; mi < 4; ++mi)
#pragma unroll
                for (int ni = 0; ni < 2; ++ni)
                    acc[mi + 4][ni] = __builtin_amdgcn_mfma_f32_16x16x32_bf16(a[mi][kk], b0[ni][kk], acc[mi + 4][ni], 0, 0, 0);
        __builtin_amdgcn_s_setprio(0);
        // drain A(t+1)+B(t+1) (and any epilogue stores); keep A(t+2) in flight
        if (sta) { asm volatile("s_waitcnt vmcnt(4)" ::: "memory"); }
        else     { asm volatile("s_waitcnt vmcnt(0)" ::: "memory"); }
        __builtin_amdgcn_s_barrier();
        asm volatile("" ::: "memory");

        // ---- m-tile epilogue: issue stores (drained by later vmcnt gates), zero acc ----
        if (tkR == NT - 1) {
            const int bm    = mtR * 32 + bmg;
            const int grow0 = bm * 256 + wm * 128 + q * 4;
            const int gcol0 = bn * 256 + wn * 64 + fr;
#pragma unroll
            for (int ei = 0; ei < 8; ++ei) {
#pragma unroll
                for (int ni = 0; ni < 4; ++ni) {
                    int gcol = gcol0 + ni * 16;
                    if (gcol < DIMV) {
                        size_t base = (size_t)(grow0 + ei * 16) * DIMV + gcol;
#pragma unroll
                        for (int r = 0; r < 4; ++r)
                            C[base + (size_t)r * DIMV] = BETA_F * acc[ei][ni][r];
                    }
                }
            }
            if (t + 1 < TT) {
#pragma unroll
                for (int ei = 0; ei < 8; ++ei)
#pragma unroll
                    for (int ni = 0; ni < 4; ++ni)
                        acc[ei][ni] = (f32x4)(0.f);
            }
            tkR = 0; ++mtR;
        } else ++tkR;

        // rotate buffers / lookahead counters
        boA = (boA == 65536) ? 0 : boA + 32768;
        stA = (stA == 65536) ? 0 : stA + 32768;
        boB ^= 32768;
        stB ^= 32768;
        if (++kb1 == NT) kb1 = 0;
        if (++ka2 == NT) { ka2 = 0; aStage += mstep; }
    }
#undef STAGE_A
#undef STAGE_B
}

extern "C" void kernel_launch(void* const* d_in, const int* in_sizes, int n_in,
                              void* d_out, int out_size, void* d_ws, size_t ws_size,
                              hipStream_t stream) {
    const float* x    = (const float*)d_in[0];
    const int*   widx = (const int*)d_in[1];
    const float* wval = (const float*)d_in[2];
    float* out = (float*)d_out;

    const int nz = in_sizes[2];
    const int M  = in_sizes[0] / DIMV;      // 32768

    const size_t xb_bytes = (size_t)M * KP * 2;          // 125,829,120
    const size_t wb_bytes = (size_t)2048 * KP * 2;       //   7,864,320
    const size_t wd_bytes = (size_t)DIMV * DIMV * 4;     //  14,592,400
    char* ws = (char*)d_ws;
    unsigned short* xb = (unsigned short*)ws;
    unsigned short* Wb = (unsigned short*)(ws + xb_bytes);
    float*          Wd = (float*)(ws + xb_bytes + wb_bytes);
    if (ws_size < xb_bytes + wb_bytes + wd_bytes) return;

    hipMemsetAsync(Wd, 0, wd_bytes, stream);
    k_prep<<<2048, 256, 0, stream>>>(x, xb, M * KP / 8, widx, widx + nz, wval, Wd, nz);
    k_build_w<<<1800, 256, 0, stream>>>(Wd, Wb, KP * KP / 8);
    k_gemm<<<256, 512, 0, stream>>>((const short*)xb, (const short*)Wb, out);
}